// Round 18
// baseline (237.649 us; speedup 1.0000x reference)
//
#include <hip/hip_runtime.h>
#include <hip/hip_bf16.h>

#define HID 128

typedef __attribute__((ext_vector_type(8))) short bf16x8;
typedef __attribute__((ext_vector_type(4))) float f32x4;
typedef __attribute__((ext_vector_type(2))) unsigned u32x2;
typedef __attribute__((ext_vector_type(4))) unsigned u32x4;

__device__ inline unsigned short f2bf(float f) {
    unsigned u = __float_as_uint(f);
    u += 0x7fffu + ((u >> 16) & 1u);   // RNE
    return (unsigned short)(u >> 16);
}
__device__ inline float bflo(unsigned u) { return __uint_as_float(u << 16); }
__device__ inline float bfhi(unsigned u) { return __uint_as_float(u & 0xffff0000u); }

// bucket for degree-descending counting sort (64 bins; deg clamped)
__device__ inline int dbucket(int d) { return 63 - min(d, 63); }

// ---------------- CSR build ----------------

__global__ void init_kernel(const float* __restrict__ W1, const float* __restrict__ W2,
                            const float* __restrict__ W3, ushort* __restrict__ wbuf,
                            int* __restrict__ deg, int* __restrict__ hist, int N) {
    int i = blockIdx.x * blockDim.x + threadIdx.x;
    if (i < N) deg[i] = 1;  // self loop
    if (i < 64) hist[i] = 0;
    if (i < 3 * 2048) {
        int layer = i >> 11;
        int rem = i & 2047;
        int lane = rem & 63;
        int tt = (rem >> 6) & 7;
        int s = rem >> 9;
        const float* W = (layer == 0) ? W1 : (layer == 1) ? W2 : W3;
        int k0 = s * 32 + (lane >> 4) * 8;
        int c = tt * 16 + (lane & 15);
        ushort out[8];
        #pragma unroll
        for (int j = 0; j < 8; ++j) out[j] = f2bf(W[(size_t)(k0 + j) * HID + c]);
        size_t base = (size_t)layer * 16384 + (((size_t)s * 8 + tt) * 64 + lane) * 8;
        *(uint4*)&wbuf[base] = *(uint4*)out;
    }
}

__global__ void deg_count_kernel(const int* __restrict__ dst, int E, int* deg) {
    int i = blockIdx.x * blockDim.x + threadIdx.x;
    if (i < E) atomicAdd(&deg[dst[i]], 1);
}

__global__ __launch_bounds__(256) void scan1_kernel(const int* __restrict__ deg,
                                                    int* __restrict__ bsum,
                                                    int* __restrict__ hist, int N) {
    __shared__ int lh[64];
    int tid = threadIdx.x;
    int i = blockIdx.x * 256 + tid;
    if (tid < 64) lh[tid] = 0;
    __syncthreads();
    int v = (i < N) ? deg[i] : 0;
    if (i < N) atomicAdd(&lh[dbucket(v)], 1);
    #pragma unroll
    for (int off = 1; off < 64; off <<= 1) v += __shfl_xor(v, off);
    __shared__ int ws[4];
    if ((tid & 63) == 0) ws[tid >> 6] = v;
    __syncthreads();
    if (tid == 0) bsum[blockIdx.x] = ws[0] + ws[1] + ws[2] + ws[3];
    if (tid < 64 && lh[tid] > 0) atomicAdd(&hist[tid], lh[tid]);
}

__global__ __launch_bounds__(256) void scan2_kernel(const int* __restrict__ bsum,
                                                    int* __restrict__ boff,
                                                    int* __restrict__ row_ptr,
                                                    const int* __restrict__ hist,
                                                    int* __restrict__ binCur, int NB, int N) {
    __shared__ int s[256];
    int tid = threadIdx.x;
    int v = (tid < NB) ? bsum[tid] : 0;
    s[tid] = v;
    __syncthreads();
    for (int off = 1; off < 256; off <<= 1) {
        int t = (tid >= off) ? s[tid - off] : 0;
        __syncthreads();
        s[tid] += t;
        __syncthreads();
    }
    if (tid < NB) boff[tid] = s[tid] - v;  // exclusive
    if (tid == NB - 1) row_ptr[N] = s[tid];
    if (tid == 0) {
        int run = 0;
        for (int b = 0; b < 64; ++b) { binCur[b] = run; run += hist[b]; }
    }
}

// rp/cursor/self-loop write + degree-sorted order scatter (LDS-aggregated — R15 lesson)
__global__ __launch_bounds__(256) void scan3_kernel(const int* __restrict__ deg,
                                                    const int* __restrict__ boff,
                                                    int* __restrict__ row_ptr,
                                                    int* __restrict__ cursor,
                                                    int* __restrict__ col,
                                                    int* __restrict__ binCur,
                                                    int* __restrict__ order, int N) {
    __shared__ int s[256];
    __shared__ int lh[64];
    __shared__ int lbase[64];
    int tid = threadIdx.x;
    int i = blockIdx.x * 256 + tid;
    if (tid < 64) lh[tid] = 0;
    int d = (i < N) ? deg[i] : 0;
    s[tid] = d;
    __syncthreads();
    int lrank = 0, bkt = dbucket(d);
    if (i < N) lrank = atomicAdd(&lh[bkt], 1);
    for (int off = 1; off < 256; off <<= 1) {
        int t = (tid >= off) ? s[tid - off] : 0;
        __syncthreads();
        s[tid] += t;
        __syncthreads();
    }
    if (tid < 64 && lh[tid] > 0) lbase[tid] = atomicAdd(&binCur[tid], lh[tid]);
    if (i < N) {
        int run = boff[blockIdx.x] + s[tid] - d;  // exclusive prefix
        row_ptr[i] = run;
        cursor[i] = run + 1;  // slot 0 taken by self loop
        col[run] = i;         // self loop
    }
    __syncthreads();
    if (i < N) order[lbase[bkt] + lrank] = i;
}

__global__ void scatter_kernel(const int* __restrict__ src, const int* __restrict__ dst,
                               int E, int* cursor, int* col) {
    int i = blockIdx.x * blockDim.x + threadIdx.x;
    if (i < E) {
        int pos = atomicAdd(&cursor[dst[i]], 1);
        col[pos] = src[i];
    }
}

// ---------------- MFMA GEMM + fused alphas (W as A-operand, 32 KB LDS W) ----------------
template <int H, bool SRC32>
__global__ __launch_bounds__(256) void mfma_gemm_kernel(const void* __restrict__ xin,
                                                        const ushort* __restrict__ wbuf,
                                                        const float* __restrict__ a_src,
                                                        const float* __restrict__ a_dst,
                                                        ushort* __restrict__ h,
                                                        float* __restrict__ pa_out,
                                                        float* __restrict__ pd_out, int N) {
    __shared__ ushort wl[16384];   // 32 KB
    int tid = threadIdx.x;
    #pragma unroll
    for (int t = 0; t < 8; ++t) {
        int i = (t * 256 + tid) * 8;
        *(uint4*)&wl[i] = *(const uint4*)&wbuf[i];
    }
    int wv = tid >> 6, lane = tid & 63;
    int r0 = blockIdx.x * 64 + wv * 16;
    int koff = (lane >> 4) * 8;

    int lrow = r0 + (lane & 15);
    if (lrow >= N) lrow = N - 1;
    bf16x8 xfrag[4];
    if (SRC32) {
        const float* xp = &((const float*)xin)[(size_t)lrow * HID + koff];
        #pragma unroll
        for (int s = 0; s < 4; ++s) {
            const f32x4* p4 = (const f32x4*)&xp[s * 32];
            f32x4 a = __builtin_nontemporal_load(p4);
            f32x4 b = __builtin_nontemporal_load(p4 + 1);
            ushort u[8] = {f2bf(a[0]), f2bf(a[1]), f2bf(a[2]), f2bf(a[3]),
                           f2bf(b[0]), f2bf(b[1]), f2bf(b[2]), f2bf(b[3])};
            xfrag[s] = *(bf16x8*)u;
        }
    } else {
        const ushort* xp = &((const ushort*)xin)[(size_t)lrow * HID + koff];
        #pragma unroll
        for (int s = 0; s < 4; ++s)
            xfrag[s] = __builtin_nontemporal_load((const bf16x8*)&xp[s * 32]);
    }
    __syncthreads();

    f32x4 acc[8];
    #pragma unroll
    for (int t = 0; t < 8; ++t) acc[t] = (f32x4){0.f, 0.f, 0.f, 0.f};

    #pragma unroll
    for (int s = 0; s < 4; ++s)
        #pragma unroll
        for (int t = 0; t < 8; ++t) {
            bf16x8 w = *(const bf16x8*)&wl[(((s * 8) + t) * 64 + lane) * 8];
            acc[t] = __builtin_amdgcn_mfma_f32_16x16x32_bf16(w, xfrag[s], acc[t], 0, 0, 0);
        }

    int row = r0 + (lane & 15);
    int cg  = lane >> 4;
    bool rowok = row < N;

    if (rowok) {
        #pragma unroll
        for (int t = 0; t < 8; ++t) {
            u32x2 pk;
            pk.x = (unsigned)f2bf(acc[t][0]) | ((unsigned)f2bf(acc[t][1]) << 16);
            pk.y = (unsigned)f2bf(acc[t][2]) | ((unsigned)f2bf(acc[t][3]) << 16);
            __builtin_nontemporal_store(pk, (u32x2*)&h[(size_t)row * HID + t * 16 + cg * 4]);
        }
    }

    if (H == 4) {
        float pah[4], pdh[4];
        #pragma unroll
        for (int hd = 0; hd < 4; ++hd) {
            float sa = 0.f, sd = 0.f;
            #pragma unroll
            for (int tt = 0; tt < 2; ++tt) {
                int t = 2 * hd + tt;
                float4 av = *(const float4*)&a_src[t * 16 + cg * 4];
                float4 dv = *(const float4*)&a_dst[t * 16 + cg * 4];
                sa += acc[t][0] * av.x + acc[t][1] * av.y + acc[t][2] * av.z + acc[t][3] * av.w;
                sd += acc[t][0] * dv.x + acc[t][1] * dv.y + acc[t][2] * dv.z + acc[t][3] * dv.w;
            }
            pah[hd] = sa; pdh[hd] = sd;
        }
        #pragma unroll
        for (int off = 16; off < 64; off <<= 1)
            #pragma unroll
            for (int hd = 0; hd < 4; ++hd) {
                pah[hd] += __shfl_xor(pah[hd], off);
                pdh[hd] += __shfl_xor(pdh[hd], off);
            }
        if (rowok && cg == 0) {
            #pragma unroll
            for (int hd = 0; hd < 4; ++hd) {
                pa_out[(size_t)row * 4 + hd] = pah[hd];
                pd_out[(size_t)row * 4 + hd] = pdh[hd];
            }
        }
    } else {
        float sa = 0.f, sd = 0.f;
        #pragma unroll
        for (int t = 0; t < 8; ++t) {
            float4 av = *(const float4*)&a_src[t * 16 + cg * 4];
            float4 dv = *(const float4*)&a_dst[t * 16 + cg * 4];
            sa += acc[t][0] * av.x + acc[t][1] * av.y + acc[t][2] * av.z + acc[t][3] * av.w;
            sd += acc[t][0] * dv.x + acc[t][1] * dv.y + acc[t][2] * dv.z + acc[t][3] * dv.w;
        }
        sa += __shfl_xor(sa, 16); sa += __shfl_xor(sa, 32);
        sd += __shfl_xor(sd, 16); sd += __shfl_xor(sd, 32);
        if (rowok && cg == 0) { pa_out[row] = sa; pd_out[row] = sd; }
    }
}

// ---------------- aggregation: XCD-sliced, fully lane-local softmax ----------------
// slice = blockIdx.x % 4 -> under round-robin XCD dispatch, slice s is pinned to XCDs
// {s, s+4}: per-XCD h working set = 50000 x 64 B = 3.2 MB < 4 MiB L2 -> repeat gathers
// become L2 hits instead of crossing the fabric (~3 TB/s path).
// Block = 4 waves x 16 nodes; lane = node*4 + c4; lane owns channels slice*32+c4*8..+7
// AND its node's softmax state for head=slice (scores recomputed redundantly per lane
// — VALU is 4% busy, free). ZERO cross-lane ops except the once-per-node dmax reduce.
// 2-edge unroll; invalid-slot gather regs zeroed (R11); low VGPR -> 8 waves/SIMD (R13).
template <int H, bool RELU, bool OUTBF>
__global__ __launch_bounds__(256) void aggregate_kernel(const ushort* __restrict__ h,
                                                        const float* __restrict__ asrc,
                                                        const float* __restrict__ adst,
                                                        const int* __restrict__ rp,
                                                        const int* __restrict__ col,
                                                        const int* __restrict__ order,
                                                        const float* __restrict__ bias,
                                                        void* __restrict__ outv, int N) {
    int slice = blockIdx.x & 3;
    int nb    = blockIdx.x >> 2;          // node-block index
    int wv    = threadIdx.x >> 6;
    int lane  = threadIdx.x & 63;
    int ng    = lane >> 2;                // node within wave (0..15)
    int c4    = lane & 3;                 // channel quad within slice (8 ch = 16 B)
    int idx   = nb * 64 + wv * 16 + ng;
    bool active = idx < N;
    int node = order[active ? idx : N - 1];
    int start = rp[node], end = rp[node + 1];
    int deg = end - start;                // >= 1 (self loop)
    int dmax = deg;
    dmax = max(dmax, __shfl_xor(dmax, 4));
    dmax = max(dmax, __shfl_xor(dmax, 8));
    dmax = max(dmax, __shfl_xor(dmax, 16));
    dmax = max(dmax, __shfl_xor(dmax, 32));
    int hd = (H == 4) ? slice : 0;
    float adst_n = adst[(size_t)node * H + hd];
    int chbase = slice * 32 + c4 * 8;     // this lane's 8 channels

    float m = -INFINITY, den = 0.f;
    float acc[8] = {0.f, 0.f, 0.f, 0.f, 0.f, 0.f, 0.f, 0.f};
    const uint4 zero4 = make_uint4(0u, 0u, 0u, 0u);

    for (int it = 0; it < dmax; it += 2) {
        bool v1 = it < deg, v2 = it + 1 < deg;
        int s1 = v1 ? col[start + it] : 0;
        int s2 = v2 ? col[start + it + 1] : 0;
        uint4 h1 = zero4, h2 = zero4;
        if (v1) h1 = *(const uint4*)&h[(size_t)s1 * HID + chbase];
        if (v2) h2 = *(const uint4*)&h[(size_t)s2 * HID + chbase];
        float e1 = -INFINITY, e2 = -INFINITY;
        if (v1) { float t = asrc[(size_t)s1 * H + hd] + adst_n; e1 = (t >= 0.f) ? t : 0.2f * t; }
        if (v2) { float t = asrc[(size_t)s2 * H + hd] + adst_n; e2 = (t >= 0.f) ? t : 0.2f * t; }
        float nm = fmaxf(m, fmaxf(e1, e2));
        float sc = __expf(m - nm);        // first iter: exp(-inf)=0; done-node: 1
        float p1 = v1 ? __expf(e1 - nm) : 0.f;
        float p2 = v2 ? __expf(e2 - nm) : 0.f;
        den = den * sc + (p1 + p2);
        m = nm;
        acc[0] = acc[0] * sc + p1 * bflo(h1.x) + p2 * bflo(h2.x);
        acc[1] = acc[1] * sc + p1 * bfhi(h1.x) + p2 * bfhi(h2.x);
        acc[2] = acc[2] * sc + p1 * bflo(h1.y) + p2 * bflo(h2.y);
        acc[3] = acc[3] * sc + p1 * bfhi(h1.y) + p2 * bfhi(h2.y);
        acc[4] = acc[4] * sc + p1 * bflo(h1.z) + p2 * bflo(h2.z);
        acc[5] = acc[5] * sc + p1 * bfhi(h1.z) + p2 * bfhi(h2.z);
        acc[6] = acc[6] * sc + p1 * bflo(h1.w) + p2 * bflo(h2.w);
        acc[7] = acc[7] * sc + p1 * bfhi(h1.w) + p2 * bfhi(h2.w);
    }

    if (active) {
        float inv = 1.f / den;
        float o[8];
        #pragma unroll
        for (int k = 0; k < 8; ++k) {
            o[k] = acc[k] * inv + bias[chbase + k];
            if (RELU) o[k] = fmaxf(o[k], 0.f);
        }
        if (OUTBF) {
            u32x4 ov;
            ov.x = (unsigned)f2bf(o[0]) | ((unsigned)f2bf(o[1]) << 16);
            ov.y = (unsigned)f2bf(o[2]) | ((unsigned)f2bf(o[3]) << 16);
            ov.z = (unsigned)f2bf(o[4]) | ((unsigned)f2bf(o[5]) << 16);
            ov.w = (unsigned)f2bf(o[6]) | ((unsigned)f2bf(o[7]) << 16);
            __builtin_nontemporal_store(ov, (u32x4*)&((ushort*)outv)[(size_t)node * HID + chbase]);
        } else {
            float* op = &((float*)outv)[(size_t)node * HID + chbase];
            f32x4 o0 = {o[0], o[1], o[2], o[3]};
            f32x4 o1 = {o[4], o[5], o[6], o[7]};
            __builtin_nontemporal_store(o0, (f32x4*)op);
            __builtin_nontemporal_store(o1, (f32x4*)(op + 4));
        }
    }
}

// ---------------- launch ----------------

extern "C" void kernel_launch(void* const* d_in, const int* in_sizes, int n_in,
                              void* d_out, int out_size, void* d_ws, size_t ws_size,
                              hipStream_t stream) {
    const float* x   = (const float*)d_in[0];
    const int*   ei  = (const int*)d_in[1];
    const float* W1  = (const float*)d_in[2];
    const float* as1 = (const float*)d_in[3];
    const float* ad1 = (const float*)d_in[4];
    const float* b1  = (const float*)d_in[5];
    const float* W2  = (const float*)d_in[6];
    const float* as2 = (const float*)d_in[7];
    const float* ad2 = (const float*)d_in[8];
    const float* b2  = (const float*)d_in[9];
    const float* W3  = (const float*)d_in[10];
    const float* as3 = (const float*)d_in[11];
    const float* ad3 = (const float*)d_in[12];
    const float* b3  = (const float*)d_in[13];

    int N = in_sizes[0] / HID;
    int E = in_sizes[1] / 2;
    const int* srcv = ei;
    const int* dstv = ei + E;

    char* ws = (char*)d_ws;
    size_t ofs = 0;
    auto alloc = [&](size_t bytes) -> void* {
        void* p = ws + ofs;
        ofs = (ofs + bytes + 255) & ~(size_t)255;
        return p;
    };
    int NB = (N + 255) / 256;
    int*    rp    = (int*)alloc((size_t)(N + 1) * 4);
    int*    cur   = (int*)alloc((size_t)N * 4);
    int*    deg   = (int*)alloc((size_t)N * 4);
    int*    bsum  = (int*)alloc((size_t)NB * 4);
    int*    boff  = (int*)alloc((size_t)NB * 4);
    int*    hist  = (int*)alloc(64 * 4);
    int*    binc  = (int*)alloc(64 * 4);
    int*    order = (int*)alloc((size_t)N * 4);
    int*    col   = (int*)alloc((size_t)(E + N) * 4);
    ushort* ys    = (ushort*)alloc((size_t)N * HID * 2);   // layer-1 out (bf16)
    ushort* zs    = (ushort*)alloc((size_t)N * HID * 2);   // layer-2 out (bf16)
    ushort* hb    = (ushort*)alloc((size_t)N * HID * 2);   // per-layer h (bf16)
    ushort* wbuf  = (ushort*)alloc((size_t)3 * 16384 * 2); // W frag layout x3
    float*  pa    = (float*)alloc((size_t)N * 4 * 4);
    float*  pd    = (float*)alloc((size_t)N * 4 * 4);

    // CSR build + W prep + degree-sort
    init_kernel<<<(N + 255) / 256, 256, 0, stream>>>(W1, W2, W3, wbuf, deg, hist, N);
    deg_count_kernel<<<(E + 255) / 256, 256, 0, stream>>>(dstv, E, deg);
    scan1_kernel<<<NB, 256, 0, stream>>>(deg, bsum, hist, N);
    scan2_kernel<<<1, 256, 0, stream>>>(bsum, boff, rp, hist, binc, NB, N);
    scan3_kernel<<<NB, 256, 0, stream>>>(deg, boff, rp, cur, col, binc, order, N);
    scatter_kernel<<<(E + 255) / 256, 256, 0, stream>>>(srcv, dstv, E, cur, col);

    int gGemm = (N + 63) / 64;
    int gAgg  = ((N + 63) / 64) * 4;   // 64 nodes per block x 4 slices

    // layer 1 (4 heads, relu): fp32 x in -> ys
    mfma_gemm_kernel<4, true><<<gGemm, 256, 0, stream>>>(x, wbuf, as1, ad1, hb, pa, pd, N);
    aggregate_kernel<4, true, true><<<gAgg, 256, 0, stream>>>(hb, pa, pd, rp, col, order, b1, ys, N);
    // layer 2 (4 heads, relu) -> zs
    mfma_gemm_kernel<4, false><<<gGemm, 256, 0, stream>>>(ys, wbuf + 16384, as2, ad2, hb, pa, pd, N);
    aggregate_kernel<4, true, true><<<gAgg, 256, 0, stream>>>(hb, pa, pd, rp, col, order, b2, zs, N);
    // layer 3 (1 head, no relu) -> d_out fp32
    mfma_gemm_kernel<1, false><<<gGemm, 256, 0, stream>>>(zs, wbuf + 32768, as3, ad3, hb, pa, pd, N);
    aggregate_kernel<1, false, false><<<gAgg, 256, 0, stream>>>(hb, pa, pd, rp, col, order, b3, d_out, N);
}

// Round 19
// 185.046 us; speedup vs baseline: 1.2843x; 1.2843x over previous
//
#include <hip/hip_runtime.h>
#include <hip/hip_bf16.h>

#define HID 128

typedef __attribute__((ext_vector_type(8))) short bf16x8;
typedef __attribute__((ext_vector_type(4))) float f32x4;
typedef __attribute__((ext_vector_type(2))) unsigned u32x2;
typedef __attribute__((ext_vector_type(4))) unsigned u32x4;

__device__ inline unsigned short f2bf(float f) {
    unsigned u = __float_as_uint(f);
    u += 0x7fffu + ((u >> 16) & 1u);   // RNE
    return (unsigned short)(u >> 16);
}
__device__ inline float bflo(unsigned u) { return __uint_as_float(u << 16); }
__device__ inline float bfhi(unsigned u) { return __uint_as_float(u & 0xffff0000u); }

// bucket for degree-descending counting sort (64 bins; deg clamped)
__device__ inline int dbucket(int d) { return 63 - min(d, 63); }

// ---------------- CSR build ----------------

__global__ void init_kernel(const float* __restrict__ W1, const float* __restrict__ W2,
                            const float* __restrict__ W3, ushort* __restrict__ wbuf,
                            int* __restrict__ deg, int* __restrict__ hist, int N) {
    int i = blockIdx.x * blockDim.x + threadIdx.x;
    if (i < N) deg[i] = 1;  // self loop
    if (i < 64) hist[i] = 0;
    if (i < 3 * 2048) {
        int layer = i >> 11;
        int rem = i & 2047;
        int lane = rem & 63;
        int tt = (rem >> 6) & 7;
        int s = rem >> 9;
        const float* W = (layer == 0) ? W1 : (layer == 1) ? W2 : W3;
        int k0 = s * 32 + (lane >> 4) * 8;
        int c = tt * 16 + (lane & 15);
        ushort out[8];
        #pragma unroll
        for (int j = 0; j < 8; ++j) out[j] = f2bf(W[(size_t)(k0 + j) * HID + c]);
        size_t base = (size_t)layer * 16384 + (((size_t)s * 8 + tt) * 64 + lane) * 8;
        *(uint4*)&wbuf[base] = *(uint4*)out;
    }
}

__global__ void deg_count_kernel(const int* __restrict__ dst, int E, int* deg) {
    int i = blockIdx.x * blockDim.x + threadIdx.x;
    if (i < E) atomicAdd(&deg[dst[i]], 1);
}

__global__ __launch_bounds__(256) void scan1_kernel(const int* __restrict__ deg,
                                                    int* __restrict__ bsum,
                                                    int* __restrict__ hist, int N) {
    __shared__ int lh[64];
    int tid = threadIdx.x;
    int i = blockIdx.x * 256 + tid;
    if (tid < 64) lh[tid] = 0;
    __syncthreads();
    int v = (i < N) ? deg[i] : 0;
    if (i < N) atomicAdd(&lh[dbucket(v)], 1);
    #pragma unroll
    for (int off = 1; off < 64; off <<= 1) v += __shfl_xor(v, off);
    __shared__ int ws[4];
    if ((tid & 63) == 0) ws[tid >> 6] = v;
    __syncthreads();
    if (tid == 0) bsum[blockIdx.x] = ws[0] + ws[1] + ws[2] + ws[3];
    if (tid < 64 && lh[tid] > 0) atomicAdd(&hist[tid], lh[tid]);
}

__global__ __launch_bounds__(256) void scan2_kernel(const int* __restrict__ bsum,
                                                    int* __restrict__ boff,
                                                    int* __restrict__ row_ptr,
                                                    const int* __restrict__ hist,
                                                    int* __restrict__ binCur, int NB, int N) {
    __shared__ int s[256];
    int tid = threadIdx.x;
    int v = (tid < NB) ? bsum[tid] : 0;
    s[tid] = v;
    __syncthreads();
    for (int off = 1; off < 256; off <<= 1) {
        int t = (tid >= off) ? s[tid - off] : 0;
        __syncthreads();
        s[tid] += t;
        __syncthreads();
    }
    if (tid < NB) boff[tid] = s[tid] - v;  // exclusive
    if (tid == NB - 1) row_ptr[N] = s[tid];
    if (tid == 0) {
        int run = 0;
        for (int b = 0; b < 64; ++b) { binCur[b] = run; run += hist[b]; }
    }
}

// rp/cursor/self-loop write + degree-sorted order scatter (LDS-aggregated — R15 lesson)
__global__ __launch_bounds__(256) void scan3_kernel(const int* __restrict__ deg,
                                                    const int* __restrict__ boff,
                                                    int* __restrict__ row_ptr,
                                                    int* __restrict__ cursor,
                                                    int* __restrict__ col,
                                                    int* __restrict__ binCur,
                                                    int* __restrict__ order, int N) {
    __shared__ int s[256];
    __shared__ int lh[64];
    __shared__ int lbase[64];
    int tid = threadIdx.x;
    int i = blockIdx.x * 256 + tid;
    if (tid < 64) lh[tid] = 0;
    int d = (i < N) ? deg[i] : 0;
    s[tid] = d;
    __syncthreads();
    int lrank = 0, bkt = dbucket(d);
    if (i < N) lrank = atomicAdd(&lh[bkt], 1);
    for (int off = 1; off < 256; off <<= 1) {
        int t = (tid >= off) ? s[tid - off] : 0;
        __syncthreads();
        s[tid] += t;
        __syncthreads();
    }
    if (tid < 64 && lh[tid] > 0) lbase[tid] = atomicAdd(&binCur[tid], lh[tid]);
    if (i < N) {
        int run = boff[blockIdx.x] + s[tid] - d;  // exclusive prefix
        row_ptr[i] = run;
        cursor[i] = run + 1;  // slot 0 taken by self loop
        col[run] = i;         // self loop
    }
    __syncthreads();
    if (i < N) order[lbase[bkt] + lrank] = i;
}

__global__ void scatter_kernel(const int* __restrict__ src, const int* __restrict__ dst,
                               int E, int* cursor, int* col) {
    int i = blockIdx.x * blockDim.x + threadIdx.x;
    if (i < E) {
        int pos = atomicAdd(&cursor[dst[i]], 1);
        col[pos] = src[i];
    }
}

// ---------------- MFMA GEMM + fused alphas (W as A-operand, 32 KB LDS W) ----------------
template <int H, bool SRC32>
__global__ __launch_bounds__(256) void mfma_gemm_kernel(const void* __restrict__ xin,
                                                        const ushort* __restrict__ wbuf,
                                                        const float* __restrict__ a_src,
                                                        const float* __restrict__ a_dst,
                                                        ushort* __restrict__ h,
                                                        float* __restrict__ pa_out,
                                                        float* __restrict__ pd_out, int N) {
    __shared__ ushort wl[16384];   // 32 KB
    int tid = threadIdx.x;
    #pragma unroll
    for (int t = 0; t < 8; ++t) {
        int i = (t * 256 + tid) * 8;
        *(uint4*)&wl[i] = *(const uint4*)&wbuf[i];
    }
    int wv = tid >> 6, lane = tid & 63;
    int r0 = blockIdx.x * 64 + wv * 16;
    int koff = (lane >> 4) * 8;

    int lrow = r0 + (lane & 15);
    if (lrow >= N) lrow = N - 1;
    bf16x8 xfrag[4];
    if (SRC32) {
        const float* xp = &((const float*)xin)[(size_t)lrow * HID + koff];
        #pragma unroll
        for (int s = 0; s < 4; ++s) {
            const f32x4* p4 = (const f32x4*)&xp[s * 32];
            f32x4 a = __builtin_nontemporal_load(p4);
            f32x4 b = __builtin_nontemporal_load(p4 + 1);
            ushort u[8] = {f2bf(a[0]), f2bf(a[1]), f2bf(a[2]), f2bf(a[3]),
                           f2bf(b[0]), f2bf(b[1]), f2bf(b[2]), f2bf(b[3])};
            xfrag[s] = *(bf16x8*)u;
        }
    } else {
        const ushort* xp = &((const ushort*)xin)[(size_t)lrow * HID + koff];
        #pragma unroll
        for (int s = 0; s < 4; ++s)
            xfrag[s] = __builtin_nontemporal_load((const bf16x8*)&xp[s * 32]);
    }
    __syncthreads();

    f32x4 acc[8];
    #pragma unroll
    for (int t = 0; t < 8; ++t) acc[t] = (f32x4){0.f, 0.f, 0.f, 0.f};

    #pragma unroll
    for (int s = 0; s < 4; ++s)
        #pragma unroll
        for (int t = 0; t < 8; ++t) {
            bf16x8 w = *(const bf16x8*)&wl[(((s * 8) + t) * 64 + lane) * 8];
            acc[t] = __builtin_amdgcn_mfma_f32_16x16x32_bf16(w, xfrag[s], acc[t], 0, 0, 0);
        }

    int row = r0 + (lane & 15);
    int cg  = lane >> 4;
    bool rowok = row < N;

    if (rowok) {
        #pragma unroll
        for (int t = 0; t < 8; ++t) {
            u32x2 pk;
            pk.x = (unsigned)f2bf(acc[t][0]) | ((unsigned)f2bf(acc[t][1]) << 16);
            pk.y = (unsigned)f2bf(acc[t][2]) | ((unsigned)f2bf(acc[t][3]) << 16);
            __builtin_nontemporal_store(pk, (u32x2*)&h[(size_t)row * HID + t * 16 + cg * 4]);
        }
    }

    if (H == 4) {
        float pah[4], pdh[4];
        #pragma unroll
        for (int hd = 0; hd < 4; ++hd) {
            float sa = 0.f, sd = 0.f;
            #pragma unroll
            for (int tt = 0; tt < 2; ++tt) {
                int t = 2 * hd + tt;
                float4 av = *(const float4*)&a_src[t * 16 + cg * 4];
                float4 dv = *(const float4*)&a_dst[t * 16 + cg * 4];
                sa += acc[t][0] * av.x + acc[t][1] * av.y + acc[t][2] * av.z + acc[t][3] * av.w;
                sd += acc[t][0] * dv.x + acc[t][1] * dv.y + acc[t][2] * dv.z + acc[t][3] * dv.w;
            }
            pah[hd] = sa; pdh[hd] = sd;
        }
        #pragma unroll
        for (int off = 16; off < 64; off <<= 1)
            #pragma unroll
            for (int hd = 0; hd < 4; ++hd) {
                pah[hd] += __shfl_xor(pah[hd], off);
                pdh[hd] += __shfl_xor(pdh[hd], off);
            }
        if (rowok && cg == 0) {
            #pragma unroll
            for (int hd = 0; hd < 4; ++hd) {
                pa_out[(size_t)row * 4 + hd] = pah[hd];
                pd_out[(size_t)row * 4 + hd] = pdh[hd];
            }
        }
    } else {
        float sa = 0.f, sd = 0.f;
        #pragma unroll
        for (int t = 0; t < 8; ++t) {
            float4 av = *(const float4*)&a_src[t * 16 + cg * 4];
            float4 dv = *(const float4*)&a_dst[t * 16 + cg * 4];
            sa += acc[t][0] * av.x + acc[t][1] * av.y + acc[t][2] * av.z + acc[t][3] * av.w;
            sd += acc[t][0] * dv.x + acc[t][1] * dv.y + acc[t][2] * dv.z + acc[t][3] * dv.w;
        }
        sa += __shfl_xor(sa, 16); sa += __shfl_xor(sa, 32);
        sd += __shfl_xor(sd, 16); sd += __shfl_xor(sd, 32);
        if (rowok && cg == 0) { pa_out[row] = sa; pd_out[row] = sd; }
    }
}

// ---------------- aggregation: ZERO-shuffle, 16-lane group per node, 4-edge unroll ----------------
// Degree-sorted order; low VGPR keeps 8 waves/SIMD (R13 lesson); invalid-slot gather
// regs zeroed (R11 lesson). Gather loads cached; output stores NT.
template <int H, bool RELU, bool OUTBF>
__global__ __launch_bounds__(256) void aggregate_kernel(const ushort* __restrict__ h,
                                                        const float* __restrict__ asrc,
                                                        const float* __restrict__ adst,
                                                        const int* __restrict__ rp,
                                                        const int* __restrict__ col,
                                                        const int* __restrict__ order,
                                                        const float* __restrict__ bias,
                                                        void* __restrict__ outv, int N) {
    int lane = threadIdx.x & 63;
    int wid  = blockIdx.x * 4 + (threadIdx.x >> 6);
    int g  = lane >> 4;
    int cl = lane & 15;
    int idx = wid * 4 + g;
    bool active = idx < N;
    int node = order[active ? idx : N - 1];
    int start = rp[node], end = rp[node + 1];
    int deg = end - start;                 // >= 1 (self loop)
    int dmax = deg;
    dmax = max(dmax, __shfl_xor(dmax, 16));
    dmax = max(dmax, __shfl_xor(dmax, 32));
    int ahd = (H == 4) ? (cl >> 2) : 0;
    float adst_n = adst[(size_t)node * H + ahd];

    float m = -INFINITY, den = 0.f;
    float acc[8] = {0.f, 0.f, 0.f, 0.f, 0.f, 0.f, 0.f, 0.f};
    const uint4 zero4 = make_uint4(0u, 0u, 0u, 0u);

    for (int it = 0; it < dmax; it += 4) {
        bool v1 = it < deg, v2 = it + 1 < deg, v3 = it + 2 < deg, v4 = it + 3 < deg;
        int s1 = v1 ? col[start + it] : 0;
        int s2 = v2 ? col[start + it + 1] : 0;
        int s3 = v3 ? col[start + it + 2] : 0;
        int s4 = v4 ? col[start + it + 3] : 0;
        uint4 h1 = zero4, h2 = zero4, h3 = zero4, h4 = zero4;
        if (v1) h1 = *(const uint4*)&h[(size_t)s1 * HID + cl * 8];
        if (v2) h2 = *(const uint4*)&h[(size_t)s2 * HID + cl * 8];
        if (v3) h3 = *(const uint4*)&h[(size_t)s3 * HID + cl * 8];
        if (v4) h4 = *(const uint4*)&h[(size_t)s4 * HID + cl * 8];
        float e1 = -INFINITY, e2 = -INFINITY, e3 = -INFINITY, e4 = -INFINITY;
        if (v1) { float t = asrc[(size_t)s1 * H + ahd] + adst_n; e1 = (t >= 0.f) ? t : 0.2f * t; }
        if (v2) { float t = asrc[(size_t)s2 * H + ahd] + adst_n; e2 = (t >= 0.f) ? t : 0.2f * t; }
        if (v3) { float t = asrc[(size_t)s3 * H + ahd] + adst_n; e3 = (t >= 0.f) ? t : 0.2f * t; }
        if (v4) { float t = asrc[(size_t)s4 * H + ahd] + adst_n; e4 = (t >= 0.f) ? t : 0.2f * t; }
        float nm = fmaxf(fmaxf(m, fmaxf(e1, e2)), fmaxf(e3, e4));
        float sc = __expf(m - nm);         // first iter: exp(-inf)=0; done-group: 1
        float p1 = v1 ? __expf(e1 - nm) : 0.f;
        float p2 = v2 ? __expf(e2 - nm) : 0.f;
        float p3 = v3 ? __expf(e3 - nm) : 0.f;
        float p4 = v4 ? __expf(e4 - nm) : 0.f;
        den = den * sc + ((p1 + p2) + (p3 + p4));
        m = nm;
        acc[0] = acc[0] * sc + p1 * bflo(h1.x) + p2 * bflo(h2.x) + p3 * bflo(h3.x) + p4 * bflo(h4.x);
        acc[1] = acc[1] * sc + p1 * bfhi(h1.x) + p2 * bfhi(h2.x) + p3 * bfhi(h3.x) + p4 * bfhi(h4.x);
        acc[2] = acc[2] * sc + p1 * bflo(h1.y) + p2 * bflo(h2.y) + p3 * bflo(h3.y) + p4 * bflo(h4.y);
        acc[3] = acc[3] * sc + p1 * bfhi(h1.y) + p2 * bfhi(h2.y) + p3 * bfhi(h3.y) + p4 * bfhi(h4.y);
        acc[4] = acc[4] * sc + p1 * bflo(h1.z) + p2 * bflo(h2.z) + p3 * bflo(h3.z) + p4 * bflo(h4.z);
        acc[5] = acc[5] * sc + p1 * bfhi(h1.z) + p2 * bfhi(h2.z) + p3 * bfhi(h3.z) + p4 * bfhi(h4.z);
        acc[6] = acc[6] * sc + p1 * bflo(h1.w) + p2 * bflo(h2.w) + p3 * bflo(h3.w) + p4 * bflo(h4.w);
        acc[7] = acc[7] * sc + p1 * bfhi(h1.w) + p2 * bfhi(h2.w) + p3 * bfhi(h3.w) + p4 * bfhi(h4.w);
    }

    if (active) {
        float inv = 1.f / den;
        float o[8];
        #pragma unroll
        for (int k = 0; k < 8; ++k) {
            o[k] = acc[k] * inv + bias[cl * 8 + k];
            if (RELU) o[k] = fmaxf(o[k], 0.f);
        }
        if (OUTBF) {
            u32x4 ov;
            ov.x = (unsigned)f2bf(o[0]) | ((unsigned)f2bf(o[1]) << 16);
            ov.y = (unsigned)f2bf(o[2]) | ((unsigned)f2bf(o[3]) << 16);
            ov.z = (unsigned)f2bf(o[4]) | ((unsigned)f2bf(o[5]) << 16);
            ov.w = (unsigned)f2bf(o[6]) | ((unsigned)f2bf(o[7]) << 16);
            __builtin_nontemporal_store(ov, (u32x4*)&((ushort*)outv)[(size_t)node * HID + cl * 8]);
        } else {
            float* op = &((float*)outv)[(size_t)node * HID + cl * 8];
            f32x4 o0 = {o[0], o[1], o[2], o[3]};
            f32x4 o1 = {o[4], o[5], o[6], o[7]};
            __builtin_nontemporal_store(o0, (f32x4*)op);
            __builtin_nontemporal_store(o1, (f32x4*)(op + 4));
        }
    }
}

// ---------------- launch ----------------

extern "C" void kernel_launch(void* const* d_in, const int* in_sizes, int n_in,
                              void* d_out, int out_size, void* d_ws, size_t ws_size,
                              hipStream_t stream) {
    const float* x   = (const float*)d_in[0];
    const int*   ei  = (const int*)d_in[1];
    const float* W1  = (const float*)d_in[2];
    const float* as1 = (const float*)d_in[3];
    const float* ad1 = (const float*)d_in[4];
    const float* b1  = (const float*)d_in[5];
    const float* W2  = (const float*)d_in[6];
    const float* as2 = (const float*)d_in[7];
    const float* ad2 = (const float*)d_in[8];
    const float* b2  = (const float*)d_in[9];
    const float* W3  = (const float*)d_in[10];
    const float* as3 = (const float*)d_in[11];
    const float* ad3 = (const float*)d_in[12];
    const float* b3  = (const float*)d_in[13];

    int N = in_sizes[0] / HID;
    int E = in_sizes[1] / 2;
    const int* srcv = ei;
    const int* dstv = ei + E;

    char* ws = (char*)d_ws;
    size_t ofs = 0;
    auto alloc = [&](size_t bytes) -> void* {
        void* p = ws + ofs;
        ofs = (ofs + bytes + 255) & ~(size_t)255;
        return p;
    };
    int NB = (N + 255) / 256;
    int*    rp    = (int*)alloc((size_t)(N + 1) * 4);
    int*    cur   = (int*)alloc((size_t)N * 4);
    int*    deg   = (int*)alloc((size_t)N * 4);
    int*    bsum  = (int*)alloc((size_t)NB * 4);
    int*    boff  = (int*)alloc((size_t)NB * 4);
    int*    hist  = (int*)alloc(64 * 4);
    int*    binc  = (int*)alloc(64 * 4);
    int*    order = (int*)alloc((size_t)N * 4);
    int*    col   = (int*)alloc((size_t)(E + N) * 4);
    ushort* ys    = (ushort*)alloc((size_t)N * HID * 2);   // layer-1 out (bf16)
    ushort* zs    = (ushort*)alloc((size_t)N * HID * 2);   // layer-2 out (bf16)
    ushort* hb    = (ushort*)alloc((size_t)N * HID * 2);   // per-layer h (bf16)
    ushort* wbuf  = (ushort*)alloc((size_t)3 * 16384 * 2); // W frag layout x3
    float*  pa    = (float*)alloc((size_t)N * 4 * 4);
    float*  pd    = (float*)alloc((size_t)N * 4 * 4);

    // CSR build + W prep + degree-sort
    init_kernel<<<(N + 255) / 256, 256, 0, stream>>>(W1, W2, W3, wbuf, deg, hist, N);
    deg_count_kernel<<<(E + 255) / 256, 256, 0, stream>>>(dstv, E, deg);
    scan1_kernel<<<NB, 256, 0, stream>>>(deg, bsum, hist, N);
    scan2_kernel<<<1, 256, 0, stream>>>(bsum, boff, rp, hist, binc, NB, N);
    scan3_kernel<<<NB, 256, 0, stream>>>(deg, boff, rp, cur, col, binc, order, N);
    scatter_kernel<<<(E + 255) / 256, 256, 0, stream>>>(srcv, dstv, E, cur, col);

    int gGemm = (N + 63) / 64;
    int gWave = (N + 15) / 16;   // 4 nodes per wave, 4 waves per block

    // layer 1 (4 heads, relu): fp32 x in -> ys
    mfma_gemm_kernel<4, true><<<gGemm, 256, 0, stream>>>(x, wbuf, as1, ad1, hb, pa, pd, N);
    aggregate_kernel<4, true, true><<<gWave, 256, 0, stream>>>(hb, pa, pd, rp, col, order, b1, ys, N);
    // layer 2 (4 heads, relu) -> zs
    mfma_gemm_kernel<4, false><<<gGemm, 256, 0, stream>>>(ys, wbuf + 16384, as2, ad2, hb, pa, pd, N);
    aggregate_kernel<4, true, true><<<gWave, 256, 0, stream>>>(hb, pa, pd, rp, col, order, b2, zs, N);
    // layer 3 (1 head, no relu) -> d_out fp32
    mfma_gemm_kernel<1, false><<<gGemm, 256, 0, stream>>>(zs, wbuf + 32768, as3, ad3, hb, pa, pd, N);
    aggregate_kernel<1, false, false><<<gWave, 256, 0, stream>>>(hb, pa, pd, rp, col, order, b3, d_out, N);
}